// Round 6
// baseline (822.758 us; speedup 1.0000x reference)
//
#include <hip/hip_runtime.h>

// Problem constants: B=32, T=2048, V=64, H=256, HD=128.
#define BB 32
#define TT 2048
#define VV 64
#define HH 256
#define HD 128
#define G3 384  // 3*HD

typedef _Float16 h2 __attribute__((ext_vector_type(2)));
typedef _Float16 h8 __attribute__((ext_vector_type(8)));

// exp2-domain scales: sigmoid(a)=rcp(1+2^(-a*log2e)), tanh(a)=1-2*rcp(1+2^(2a*log2e))
#define SRZ (-1.4426950408889634f)  // -log2(e), r/z gates
#define SN  (2.8853900817779268f)   // +2*log2(e), n gate

// Pair sum: swap with the other lane of the pair (quad_perm[1,0,3,2]=0xB1), add.
__device__ __forceinline__ float pair_reduce_add(float v) {
  int x = __builtin_amdgcn_mov_dpp(__float_as_int(v), 0xB1, 0xF, 0xF, true);
  return v + __int_as_float(x);
}

template <int D>
__device__ __forceinline__ h2 getpair(h8 v) {
  return __builtin_shufflevector(v, v, 2 * D, 2 * D + 1);
}

// ---------------------------------------------------------------------------
// Kernel 1: gi_table[dir][v][j] = (emb[v] @ Wih_dir[j].T + bih_dir[j]) * scale_j
// ---------------------------------------------------------------------------
__global__ __launch_bounds__(G3, 1)
void gi_table_kernel(const float* __restrict__ emb,
                     const float* __restrict__ Wih_f, const float* __restrict__ bih_f,
                     const float* __restrict__ Wih_b, const float* __restrict__ bih_b,
                     float* __restrict__ gi_ws) {
  const int gid = blockIdx.x;          // 0..127
  const int dir = gid >> 6;
  const int v   = gid & 63;
  const int j   = threadIdx.x;         // 0..383
  const float* Wih = dir ? Wih_b : Wih_f;
  const float* bih = dir ? bih_b : bih_f;
  const float4* er = reinterpret_cast<const float4*>(emb + v * HH);
  const float4* wr = reinterpret_cast<const float4*>(Wih + j * HH);
  float acc = bih[j];
  #pragma unroll 8
  for (int k = 0; k < HH / 4; ++k) {
    float4 e = er[k];
    float4 w = wr[k];
    acc = fmaf(e.x, w.x, acc);
    acc = fmaf(e.y, w.y, acc);
    acc = fmaf(e.z, w.z, acc);
    acc = fmaf(e.w, w.w, acc);
  }
  const float sc = (j < 2 * HD) ? SRZ : SN;
  gi_ws[dir * (VV * G3) + v * G3 + j] = acc * sc;
}

// ---------------------------------------------------------------------------
// Kernel 2: recurrence. 64 blocks x 256 threads (4 waves, 1/SIMD).
// Pair (2 lanes) owns h-index i = wave*32 + (lane>>1); lane kh=lane&1 owns
// k-half [64kh, 64kh+64) (8 x ds_read_b128). Per gate, FOUR independent
// dot accumulators (12 chains of depth 8) so the fdot2 dependence chain is
// fully issue-pipelined; 2-level add tree + 1-stage DPP pair reduce.
// exp2-domain gates (both lanes redundant) -> b16 write to other h buffer
// (two per-k-half copies on disjoint bank halves). ONE barrier/step.
// Token offsets pre-multiplied by 384; gi prefetched 1 step ahead, token 2.
// ---------------------------------------------------------------------------
__global__ __launch_bounds__(256, 1)
void gru_kernel(const int* __restrict__ tokens, const int* __restrict__ lengths,
                const float* __restrict__ Whh_f, const float* __restrict__ bhh_f,
                const float* __restrict__ Whh_b, const float* __restrict__ bhh_b,
                const float* __restrict__ gi_ws, float* __restrict__ out) {
  __shared__ float giL[VV * G3];                    // 96 KB (pre-scaled)
  __shared__ int   tokL[TT];                        // 8 KB (tok*384)
  __shared__ __align__(16) _Float16 hb[2][2][160];  // [dbuf][khalf-copy][128+32 pad]

  const int bid  = blockIdx.x;    // 0..63
  const int b    = bid & 31;
  const int dir  = bid >> 5;
  const int tid  = threadIdx.x;   // 0..255
  const int wave = tid >> 6;
  const int lane = tid & 63;
  const int kh   = lane & 1;                 // k-half
  const int i    = wave * 32 + (lane >> 1);  // owned h index 0..127

  int len = lengths[b];
  if (len < 1) len = 1;

  // Stage gi table (float4), token offsets (pre-multiplied), zero h buffers.
  {
    const float4* gs = reinterpret_cast<const float4*>(gi_ws + dir * (VV * G3));
    float4* gd = reinterpret_cast<float4*>(giL);
    for (int idx = tid; idx < VV * G3 / 4; idx += 256) gd[idx] = gs[idx];
    const int* tb = tokens + b * TT;
    for (int s = tid; s < len; s += 256) tokL[s] = tb[dir ? (len - 1 - s) : s] * G3;
    _Float16* hz = reinterpret_cast<_Float16*>(hb);
    for (int idx = tid; idx < 2 * 2 * 160; idx += 256) hz[idx] = (_Float16)0.0f;
  }

  // Weights: rows {i, 128+i, 256+i}, k-half [64kh,64kh+64), exp2-pre-scaled.
  const float* Whh = dir ? Whh_b : Whh_f;
  const float* bhh = dir ? bhh_b : bhh_f;
  h8 w8[3][8];
  #pragma unroll
  for (int g = 0; g < 3; ++g) {
    const float sc = (g < 2) ? SRZ : SN;
    const float* wr = Whh + (g * HD + i) * HD + kh * 64;
    #pragma unroll
    for (int c = 0; c < 8; ++c) {
      h8 w;
      #pragma unroll
      for (int d = 0; d < 8; ++d) w[d] = (_Float16)(wr[c * 8 + d] * sc);
      w8[g][c] = w;
    }
  }
  const float bhr = bhh[i] * SRZ;
  const float bhz = bhh[HD + i] * SRZ;
  const float bhn = bhh[2 * HD + i] * SN;

  __syncthreads();

  float h = 0.0f, hsum = 0.0f;

  int tokOff = tokL[0];
  float gr = giL[tokOff + i];
  float gz = giL[tokOff + HD + i];
  float gn = giL[tokOff + 2 * HD + i];
  int ntokOff = tokL[(1 < len) ? 1 : 0];

#define DOT8(acc, wv, hv)                                                   \
  acc = __builtin_amdgcn_fdot2(getpair<0>(wv), getpair<0>(hv), acc, false); \
  acc = __builtin_amdgcn_fdot2(getpair<1>(wv), getpair<1>(hv), acc, false); \
  acc = __builtin_amdgcn_fdot2(getpair<2>(wv), getpair<2>(hv), acc, false); \
  acc = __builtin_amdgcn_fdot2(getpair<3>(wv), getpair<3>(hv), acc, false)

  #pragma unroll 2
  for (int s = 0; s < len; ++s) {
    const int cur = s & 1;
    // This lane's k-half slice of h: 8 x b128, broadcast + disjoint banks.
    const h8* hv8 = reinterpret_cast<const h8*>(&hb[cur][kh][kh * 64]);
    const h8 hv0 = hv8[0], hv1 = hv8[1], hv2 = hv8[2], hv3 = hv8[3];
    const h8 hv4 = hv8[4], hv5 = hv8[5], hv6 = hv8[6], hv7 = hv8[7];

    // Prefetch next step's gi and the token offset after that.
    const float ngr = giL[ntokOff + i];
    const float ngz = giL[ntokOff + HD + i];
    const float ngn = giL[ntokOff + 2 * HD + i];
    int s2 = s + 2;
    if (s2 >= len) s2 = len - 1;
    const int nnOff = tokL[s2];

    // 4 independent accumulators per gate: chains of depth 8 (issue-pipelined).
    float ar0 = bhr, ar1 = 0.0f, ar2 = 0.0f, ar3 = 0.0f;
    float az0 = bhz, az1 = 0.0f, az2 = 0.0f, az3 = 0.0f;
    float an0 = bhn, an1 = 0.0f, an2 = 0.0f, an3 = 0.0f;
    DOT8(ar0, w8[0][0], hv0); DOT8(az0, w8[1][0], hv0); DOT8(an0, w8[2][0], hv0);
    DOT8(ar1, w8[0][1], hv1); DOT8(az1, w8[1][1], hv1); DOT8(an1, w8[2][1], hv1);
    DOT8(ar2, w8[0][2], hv2); DOT8(az2, w8[1][2], hv2); DOT8(an2, w8[2][2], hv2);
    DOT8(ar3, w8[0][3], hv3); DOT8(az3, w8[1][3], hv3); DOT8(an3, w8[2][3], hv3);
    DOT8(ar0, w8[0][4], hv4); DOT8(az0, w8[1][4], hv4); DOT8(an0, w8[2][4], hv4);
    DOT8(ar1, w8[0][5], hv5); DOT8(az1, w8[1][5], hv5); DOT8(an1, w8[2][5], hv5);
    DOT8(ar2, w8[0][6], hv6); DOT8(az2, w8[1][6], hv6); DOT8(an2, w8[2][6], hv6);
    DOT8(ar3, w8[0][7], hv7); DOT8(az3, w8[1][7], hv7); DOT8(an3, w8[2][7], hv7);

    float ar = (ar0 + ar1) + (ar2 + ar3);
    float az = (az0 + az1) + (az2 + az3);
    float an = (an0 + an1) + (an2 + an3);
    ar = pair_reduce_add(ar);
    az = pair_reduce_add(az);
    an = pair_reduce_add(an);

    // exp2-domain gates (overflow-safe; rcp(inf)=0).
    const float r = __builtin_amdgcn_rcpf(1.0f + __builtin_amdgcn_exp2f(gr + ar));
    const float z = __builtin_amdgcn_rcpf(1.0f + __builtin_amdgcn_exp2f(gz + az));
    const float tn = __builtin_amdgcn_rcpf(1.0f + __builtin_amdgcn_exp2f(fmaf(r, an, gn)));
    const float n = fmaf(-2.0f, tn, 1.0f);
    h = fmaf(z, h - n, n);
    hb[cur ^ 1][kh][i] = (_Float16)h;  // disjoint bank halves per kh, 2-way
    hsum += h;
    __syncthreads();  // single barrier per step (double-buffered h)

    gr = ngr; gz = ngz; gn = ngn; ntokOff = nnOff;
  }
#undef DOT8

  if (!(lane & 1)) out[b * HH + dir * HD + i] = hsum / (float)len;
}

// ---------------------------------------------------------------------------
extern "C" void kernel_launch(void* const* d_in, const int* in_sizes, int n_in,
                              void* d_out, int out_size, void* d_ws, size_t ws_size,
                              hipStream_t stream) {
  const int*   tokens  = (const int*)d_in[0];
  const int*   lengths = (const int*)d_in[1];
  const float* emb     = (const float*)d_in[2];
  const float* Wih_f   = (const float*)d_in[3];
  const float* Whh_f   = (const float*)d_in[4];
  const float* bih_f   = (const float*)d_in[5];
  const float* bhh_f   = (const float*)d_in[6];
  const float* Wih_b   = (const float*)d_in[7];
  const float* Whh_b   = (const float*)d_in[8];
  const float* bih_b   = (const float*)d_in[9];
  const float* bhh_b   = (const float*)d_in[10];
  float* out   = (float*)d_out;
  float* gi_ws = (float*)d_ws;  // 2*64*384*4 = 192 KB

  gi_table_kernel<<<2 * VV, G3, 0, stream>>>(emb, Wih_f, bih_f, Wih_b, bih_b, gi_ws);
  gru_kernel<<<2 * BB, 256, 0, stream>>>(tokens, lengths, Whh_f, bhh_f, Whh_b, bhh_b,
                                         gi_ws, out);
}

// Round 7
// 802.414 us; speedup vs baseline: 1.0254x; 1.0254x over previous
//
#include <hip/hip_runtime.h>

// Problem constants: B=32, T=2048, V=64, H=256, HD=128.
#define BB 32
#define TT 2048
#define VV 64
#define HH 256
#define HD 128
#define G3 384  // 3*HD

typedef _Float16 h2 __attribute__((ext_vector_type(2)));
typedef _Float16 h8 __attribute__((ext_vector_type(8)));

// exp2-domain scales: sigmoid(a)=rcp(1+2^(-a*log2e)), tanh(a)=1-2*rcp(1+2^(2a*log2e))
#define SRZ (-1.4426950408889634f)  // -log2(e), r/z gates
#define SN  (2.8853900817779268f)   // +2*log2(e), n gate

// Pair sum: swap with the other lane of the pair (quad_perm[1,0,3,2]=0xB1), add.
__device__ __forceinline__ float pair_reduce_add(float v) {
  int x = __builtin_amdgcn_mov_dpp(__float_as_int(v), 0xB1, 0xF, 0xF, true);
  return v + __int_as_float(x);
}

template <int D>
__device__ __forceinline__ h2 getpair(h8 v) {
  return __builtin_shufflevector(v, v, 2 * D, 2 * D + 1);
}

// ---------------------------------------------------------------------------
// Kernel 1: gi_table[dir][v][j] = (emb[v] @ Wih_dir[j].T + bih_dir[j]) * scale_j
// ---------------------------------------------------------------------------
__global__ __launch_bounds__(G3, 1)
void gi_table_kernel(const float* __restrict__ emb,
                     const float* __restrict__ Wih_f, const float* __restrict__ bih_f,
                     const float* __restrict__ Wih_b, const float* __restrict__ bih_b,
                     float* __restrict__ gi_ws) {
  const int gid = blockIdx.x;          // 0..127
  const int dir = gid >> 6;
  const int v   = gid & 63;
  const int j   = threadIdx.x;         // 0..383
  const float* Wih = dir ? Wih_b : Wih_f;
  const float* bih = dir ? bih_b : bih_f;
  const float4* er = reinterpret_cast<const float4*>(emb + v * HH);
  const float4* wr = reinterpret_cast<const float4*>(Wih + j * HH);
  float acc = bih[j];
  #pragma unroll 8
  for (int k = 0; k < HH / 4; ++k) {
    float4 e = er[k];
    float4 w = wr[k];
    acc = fmaf(e.x, w.x, acc);
    acc = fmaf(e.y, w.y, acc);
    acc = fmaf(e.z, w.z, acc);
    acc = fmaf(e.w, w.w, acc);
  }
  const float sc = (j < 2 * HD) ? SRZ : SN;
  gi_ws[dir * (VV * G3) + v * G3 + j] = acc * sc;
}

// ---------------------------------------------------------------------------
// Kernel 2: recurrence. 64 blocks x 256 threads (4 waves, 1/SIMD).
// Pair (2 lanes) owns h-index i = wave*32 + (lane>>1); lane kh=lane&1 owns
// k-half [64kh, 64kh+64) (8 x ds_read_b128, 2 broadcast addrs/instr on
// disjoint bank halves). 3 chained fdot2 accumulators (R4 structure; the
// R5 4-acc split regressed). Ordering: h-reads issue FIRST after the
// barrier; gi/token prefetch for step s+1 is placed AFTER the dot block
// (its ~400-cycle slack covers the LDS latency). exp2-domain gates (both
// lanes redundant) -> b16 write to other h buffer. ONE barrier per step.
// ---------------------------------------------------------------------------
__global__ __launch_bounds__(256, 1)
void gru_kernel(const int* __restrict__ tokens, const int* __restrict__ lengths,
                const float* __restrict__ Whh_f, const float* __restrict__ bhh_f,
                const float* __restrict__ Whh_b, const float* __restrict__ bhh_b,
                const float* __restrict__ gi_ws, float* __restrict__ out) {
  __shared__ float giL[VV * G3];                    // 96 KB (pre-scaled)
  __shared__ int   tokL[TT];                        // 8 KB (tok*384)
  __shared__ __align__(16) _Float16 hb[2][2][160];  // [dbuf][khalf-copy][128+32 pad]

  const int bid  = blockIdx.x;    // 0..63
  const int b    = bid & 31;
  const int dir  = bid >> 5;
  const int tid  = threadIdx.x;   // 0..255
  const int wave = tid >> 6;
  const int lane = tid & 63;
  const int kh   = lane & 1;                 // k-half
  const int i    = wave * 32 + (lane >> 1);  // owned h index 0..127

  int len = lengths[b];
  if (len < 1) len = 1;

  // Stage gi table (float4), token offsets (pre-multiplied), zero h buffers.
  {
    const float4* gs = reinterpret_cast<const float4*>(gi_ws + dir * (VV * G3));
    float4* gd = reinterpret_cast<float4*>(giL);
    for (int idx = tid; idx < VV * G3 / 4; idx += 256) gd[idx] = gs[idx];
    const int* tb = tokens + b * TT;
    for (int s = tid; s < len; s += 256) tokL[s] = tb[dir ? (len - 1 - s) : s] * G3;
    _Float16* hz = reinterpret_cast<_Float16*>(hb);
    for (int idx = tid; idx < 2 * 2 * 160; idx += 256) hz[idx] = (_Float16)0.0f;
  }

  // Weights: rows {i, 128+i, 256+i}, k-half [64kh,64kh+64), exp2-pre-scaled.
  const float* Whh = dir ? Whh_b : Whh_f;
  const float* bhh = dir ? bhh_b : bhh_f;
  h8 w8[3][8];
  #pragma unroll
  for (int g = 0; g < 3; ++g) {
    const float sc = (g < 2) ? SRZ : SN;
    const float* wr = Whh + (g * HD + i) * HD + kh * 64;
    #pragma unroll
    for (int c = 0; c < 8; ++c) {
      h8 w;
      #pragma unroll
      for (int d = 0; d < 8; ++d) w[d] = (_Float16)(wr[c * 8 + d] * sc);
      w8[g][c] = w;
    }
  }
  const float bhr = bhh[i] * SRZ;
  const float bhz = bhh[HD + i] * SRZ;
  const float bhn = bhh[2 * HD + i] * SN;

  __syncthreads();

  float h = 0.0f, hsum = 0.0f;

  float gr = giL[tokL[0] + i];
  float gz = giL[tokL[0] + HD + i];
  float gn = giL[tokL[0] + 2 * HD + i];
  int ntokOff = tokL[(1 < len) ? 1 : 0];

#define DOT8(acc, wv, hv)                                                   \
  acc = __builtin_amdgcn_fdot2(getpair<0>(wv), getpair<0>(hv), acc, false); \
  acc = __builtin_amdgcn_fdot2(getpair<1>(wv), getpair<1>(hv), acc, false); \
  acc = __builtin_amdgcn_fdot2(getpair<2>(wv), getpair<2>(hv), acc, false); \
  acc = __builtin_amdgcn_fdot2(getpair<3>(wv), getpair<3>(hv), acc, false)

  #pragma unroll 2
  for (int s = 0; s < len; ++s) {
    const int cur = s & 1;
    // h-reads FIRST after the barrier: this lane's k-half, 8 x b128,
    // 2 broadcast addresses per instr on disjoint bank halves.
    const h8* hv8 = reinterpret_cast<const h8*>(&hb[cur][kh][kh * 64]);
    const h8 hv0 = hv8[0], hv1 = hv8[1], hv2 = hv8[2], hv3 = hv8[3];
    const h8 hv4 = hv8[4], hv5 = hv8[5], hv6 = hv8[6], hv7 = hv8[7];

    float ar = bhr, az = bhz, an = bhn;
    DOT8(ar, w8[0][0], hv0); DOT8(az, w8[1][0], hv0); DOT8(an, w8[2][0], hv0);
    DOT8(ar, w8[0][1], hv1); DOT8(az, w8[1][1], hv1); DOT8(an, w8[2][1], hv1);
    DOT8(ar, w8[0][2], hv2); DOT8(az, w8[1][2], hv2); DOT8(an, w8[2][2], hv2);
    DOT8(ar, w8[0][3], hv3); DOT8(az, w8[1][3], hv3); DOT8(an, w8[2][3], hv3);
    DOT8(ar, w8[0][4], hv4); DOT8(az, w8[1][4], hv4); DOT8(an, w8[2][4], hv4);
    DOT8(ar, w8[0][5], hv5); DOT8(az, w8[1][5], hv5); DOT8(an, w8[2][5], hv5);
    DOT8(ar, w8[0][6], hv6); DOT8(az, w8[1][6], hv6); DOT8(an, w8[2][6], hv6);
    DOT8(ar, w8[0][7], hv7); DOT8(az, w8[1][7], hv7); DOT8(an, w8[2][7], hv7);

    // Prefetch for step s+1, issued AFTER the dots (slack covers latency).
    const float ngr = giL[ntokOff + i];
    const float ngz = giL[ntokOff + HD + i];
    const float ngn = giL[ntokOff + 2 * HD + i];
    int s2 = s + 2;
    if (s2 >= len) s2 = len - 1;
    const int nnOff = tokL[s2];

    float ar2 = pair_reduce_add(ar);
    float az2 = pair_reduce_add(az);
    float an2 = pair_reduce_add(an);

    // exp2-domain gates (overflow-safe; rcp(inf)=0).
    const float r = __builtin_amdgcn_rcpf(1.0f + __builtin_amdgcn_exp2f(gr + ar2));
    const float z = __builtin_amdgcn_rcpf(1.0f + __builtin_amdgcn_exp2f(gz + az2));
    const float tn = __builtin_amdgcn_rcpf(1.0f + __builtin_amdgcn_exp2f(fmaf(r, an2, gn)));
    const float n = fmaf(-2.0f, tn, 1.0f);
    h = fmaf(z, h - n, n);
    hb[cur ^ 1][kh][i] = (_Float16)h;  // disjoint bank halves per kh
    hsum += h;
    __syncthreads();  // single barrier per step (double-buffered h)

    gr = ngr; gz = ngz; gn = ngn; ntokOff = nnOff;
  }
#undef DOT8

  if (!(lane & 1)) out[b * HH + dir * HD + i] = hsum / (float)len;
}

// ---------------------------------------------------------------------------
extern "C" void kernel_launch(void* const* d_in, const int* in_sizes, int n_in,
                              void* d_out, int out_size, void* d_ws, size_t ws_size,
                              hipStream_t stream) {
  const int*   tokens  = (const int*)d_in[0];
  const int*   lengths = (const int*)d_in[1];
  const float* emb     = (const float*)d_in[2];
  const float* Wih_f   = (const float*)d_in[3];
  const float* Whh_f   = (const float*)d_in[4];
  const float* bih_f   = (const float*)d_in[5];
  const float* bhh_f   = (const float*)d_in[6];
  const float* Wih_b   = (const float*)d_in[7];
  const float* Whh_b   = (const float*)d_in[8];
  const float* bih_b   = (const float*)d_in[9];
  const float* bhh_b   = (const float*)d_in[10];
  float* out   = (float*)d_out;
  float* gi_ws = (float*)d_ws;  // 2*64*384*4 = 192 KB

  gi_table_kernel<<<2 * VV, G3, 0, stream>>>(emb, Wih_f, bih_f, Wih_b, bih_b, gi_ws);
  gru_kernel<<<2 * BB, 256, 0, stream>>>(tokens, lengths, Whh_f, bhh_f, Whh_b, bhh_b,
                                         gi_ws, out);
}